// Round 1
// baseline (124.326 us; speedup 1.0000x reference)
//
#include <hip/hip_runtime.h>

#define VOL    256
#define NPROJ  256
#define NDET   384
#define NS     256
#define PST    258            // padded stride (1-px zero border)
#define PIMG   (PST * PST)    // padded image elements
#define NBATCH 2

// Fill interior of zero-padded image copies.
__global__ void pad_copy_kernel(const float* __restrict__ src, float* __restrict__ dst) {
    int idx = blockIdx.x * blockDim.x + threadIdx.x;   // over NBATCH*VOL*VOL
    int b   = idx >> 16;
    int rem = idx & 0xFFFF;
    int y   = rem >> 8;
    int x   = rem & 0xFF;
    dst[b * PIMG + (y + 1) * PST + (x + 1)] = src[idx];
}

__global__ __launch_bounds__(256) void fanproj_kernel(const float* __restrict__ pimg,
                                                      float* __restrict__ out) {
    int tid = blockIdx.x * blockDim.x + threadIdx.x;   // b*P*D + p*D + d
    int d   = tid % NDET;
    int pb  = tid / NDET;
    int p   = pb & (NPROJ - 1);
    int b   = pb >> 8;

    // geometry constants (double-precision folded at compile time)
    const float dt = 1.4142135623730951f;              // diag / NS = sqrt(2)
    const float t0 = 219.68777079743137f;              // SID - diag/2 + 0.5*dt

    float theta = (float)p * (6.283185307179586f / (float)NPROJ);
    float st, ct;
    sincosf(theta, &st, &ct);

    float srcx = -400.0f * ct;
    float srcy = -400.0f * st;
    float off  = ((float)d - 191.5f) * 1.2f;
    float rx   = fmaf(800.0f, ct, -off * st);
    float ry   = fmaf(800.0f, st,  off * ct);
    float n2   = rx * rx + ry * ry;
    float rn   = rsqrtf(n2);
    rn = rn * (1.5f - 0.5f * n2 * rn * rn);            // one Newton step
    rx *= rn;
    ry *= rn;

    // x = px + (VOL-1)/2 folded into base; step = dt * ray
    float bx = fmaf(t0, rx, srcx) + 127.5f;
    float by = fmaf(t0, ry, srcy) + 127.5f;
    float sx = dt * rx;
    float sy = dt * ry;

    const float* img = pimg + b * PIMG;
    float acc = 0.0f;
    float sf  = 0.0f;
#pragma unroll 4
    for (int s = 0; s < NS; ++s) {
        float x = fmaf(sf, sx, bx);
        float y = fmaf(sf, sy, by);
        sf += 1.0f;
        float xf = floorf(x);
        float yf = floorf(y);
        float wx = x - xf;
        float wy = y - yf;
        int x0 = (int)xf;
        int y0 = (int)yf;
        unsigned ux = (unsigned)(x0 + 1);              // padded col of left tap
        unsigned uy = (unsigned)(y0 + 1);              // padded row of top tap
        // x0 in [-1,255] && y0 in [-1,255]: footprint fully inside padded image;
        // anything else contributes exactly 0 (both taps OOB in reference).
        if (ux <= 256u && uy <= 256u) {
            const float* tp = img + uy * PST + ux;
            float v00 = tp[0];
            float v01 = tp[1];
            float v10 = tp[PST];
            float v11 = tp[PST + 1];
            float top = fmaf(wx, v01 - v00, v00);
            float bot = fmaf(wx, v11 - v10, v10);
            acc = fmaf(wy, bot - top, top) + acc;
        }
    }
    out[tid] = acc * dt;
}

extern "C" void kernel_launch(void* const* d_in, const int* in_sizes, int n_in,
                              void* d_out, int out_size, void* d_ws, size_t ws_size,
                              hipStream_t stream) {
    const float* x  = (const float*)d_in[0];
    float* out      = (float*)d_out;
    float* pimg     = (float*)d_ws;

    // zero the padded buffers (ws is poisoned before every call)
    hipMemsetAsync(pimg, 0, (size_t)NBATCH * PIMG * sizeof(float), stream);

    int ncopy = NBATCH * VOL * VOL;                    // 131072
    pad_copy_kernel<<<ncopy / 256, 256, 0, stream>>>(x, pimg);

    int ntot = NBATCH * NPROJ * NDET;                  // 196608
    fanproj_kernel<<<ntot / 256, 256, 0, stream>>>(pimg, out);
}

// Round 2
// 123.477 us; speedup vs baseline: 1.0069x; 1.0069x over previous
//
#include <hip/hip_runtime.h>

#define VOL    256
#define NPROJ  256
#define NDET   384
#define NS     256
#define PST    258            // padded stride (1-px zero border)
#define PIMG   (PST * PST)    // padded image elements
#define NBATCH 2
#define NCHUNK 4              // S-loop split factor (one wave per chunk)
#define SCHUNK (NS / NCHUNK)  // 64 samples per thread

// Fused zero-border + interior copy: one thread per padded-image element.
__global__ void pad_fill_kernel(const float* __restrict__ src, float* __restrict__ dst) {
    int idx = blockIdx.x * blockDim.x + threadIdx.x;   // over NBATCH*PIMG
    if (idx >= NBATCH * PIMG) return;
    int b   = idx / PIMG;
    int rem = idx - b * PIMG;
    int py  = rem / PST;
    int px  = rem - py * PST;
    float v = 0.0f;
    if (px >= 1 && px <= VOL && py >= 1 && py <= VOL)
        v = src[(b << 16) + ((py - 1) << 8) + (px - 1)];
    dst[idx] = v;
}

// Block = 256 threads = 64 rays x 4 sample-chunks (chunk == wave id).
__global__ __launch_bounds__(256) void fanproj_kernel(const float* __restrict__ pimg,
                                                      float* __restrict__ out) {
    int lane  = threadIdx.x & 63;
    int chunk = threadIdx.x >> 6;                      // 0..3
    int ray   = (blockIdx.x << 6) + lane;              // b*P*D + p*D + d
    int d     = ray % NDET;
    int pb    = ray / NDET;
    int p     = pb & (NPROJ - 1);
    int b     = pb >> 8;

    const float dt = 1.4142135623730951f;              // diag / NS = sqrt(2)
    const float t0 = 219.68777079743137f;              // SID - diag/2 + 0.5*dt

    float theta = (float)p * (6.283185307179586f / (float)NPROJ);
    float st, ct;
    sincosf(theta, &st, &ct);

    float srcx = -400.0f * ct;
    float srcy = -400.0f * st;
    float off  = ((float)d - 191.5f) * 1.2f;
    float rx   = fmaf(800.0f, ct, -off * st);
    float ry   = fmaf(800.0f, st,  off * ct);
    float n2   = rx * rx + ry * ry;
    float rn   = rsqrtf(n2);
    rn = rn * (1.5f - 0.5f * n2 * rn * rn);            // one Newton step
    rx *= rn;
    ry *= rn;

    float bx = fmaf(t0, rx, srcx) + 127.5f;            // +(VOL-1)/2 folded in
    float by = fmaf(t0, ry, srcy) + 127.5f;
    float sx = dt * rx;
    float sy = dt * ry;

    const float* img = pimg + b * PIMG;
    float acc = 0.0f;
    float sf  = (float)(chunk * SCHUNK);
#pragma unroll 4
    for (int s = 0; s < SCHUNK; ++s) {
        float x = fmaf(sf, sx, bx);
        float y = fmaf(sf, sy, by);
        sf += 1.0f;
        float xf = floorf(x);
        float yf = floorf(y);
        float wx = x - xf;
        float wy = y - yf;
        int x0 = (int)xf;
        int y0 = (int)yf;
        unsigned ux = (unsigned)(x0 + 1);              // padded col of left tap
        unsigned uy = (unsigned)(y0 + 1);              // padded row of top tap
        // x0,y0 in [-1,255]: bilinear footprint fully inside padded image;
        // anything else contributes exactly 0 in the reference.
        if (ux <= 256u && uy <= 256u) {
            const float* tp = img + uy * PST + ux;
            float v00 = tp[0];
            float v01 = tp[1];
            float v10 = tp[PST];
            float v11 = tp[PST + 1];
            float top = fmaf(wx, v01 - v00, v00);
            float bot = fmaf(wx, v11 - v10, v10);
            acc = fmaf(wy, bot - top, top) + acc;
        }
    }

    // reduce the 4 chunk-partials (one per wave) through LDS
    __shared__ float part[NCHUNK - 1][64];
    if (chunk > 0) part[chunk - 1][lane] = acc;
    __syncthreads();
    if (chunk == 0) {
        acc += part[0][lane] + part[1][lane] + part[2][lane];
        out[ray] = acc * dt;
    }
}

extern "C" void kernel_launch(void* const* d_in, const int* in_sizes, int n_in,
                              void* d_out, int out_size, void* d_ws, size_t ws_size,
                              hipStream_t stream) {
    const float* x  = (const float*)d_in[0];
    float* out      = (float*)d_out;
    float* pimg     = (float*)d_ws;

    int npad = NBATCH * PIMG;                          // 133128
    pad_fill_kernel<<<(npad + 255) / 256, 256, 0, stream>>>(x, pimg);

    int nrays = NBATCH * NPROJ * NDET;                 // 196608
    fanproj_kernel<<<nrays / 64, 256, 0, stream>>>(pimg, out);  // 3072 blocks
}

// Round 3
// 114.461 us; speedup vs baseline: 1.0862x; 1.0788x over previous
//
#include <hip/hip_runtime.h>
#include <hip/hip_fp16.h>

#define VOL    256
#define NPROJ  256
#define NDET   384
#define NS     256
#define PST    258            // padded quad-grid stride (covers x0 in [-1,256])
#define PIMG   (PST * PST)
#define NBATCH 2
#define NCHUNK 4              // S-loop split factor (one wave per chunk)
#define SCHUNK (NS / NCHUNK)  // 64 samples per thread

// Build the packed bilinear-footprint texture:
//   quad[b][py][px] = fp16x4 { img[py-1][px-1], img[py-1][px],
//                              img[py  ][px-1], img[py  ][px] }   (zero outside)
// One 8B load then fetches the whole 2x2 footprint for x0=px-1, y0=py-1.
__global__ void quad_build_kernel(const float* __restrict__ src, uint2* __restrict__ dst) {
    int idx = blockIdx.x * blockDim.x + threadIdx.x;   // over NBATCH*PIMG
    if (idx >= NBATCH * PIMG) return;
    int b   = idx / PIMG;
    int rem = idx - b * PIMG;
    int py  = rem / PST;
    int px  = rem - py * PST;
    const float* im = src + (b << 16);
    int ym = py - 1, xm = px - 1;                      // unpadded coords of top-left tap
    bool yin0 = (unsigned)ym < (unsigned)VOL;
    bool yin1 = (unsigned)py < (unsigned)VOL;
    bool xin0 = (unsigned)xm < (unsigned)VOL;
    bool xin1 = (unsigned)px < (unsigned)VOL;
    float v00 = (yin0 && xin0) ? im[(ym << 8) + xm] : 0.0f;
    float v01 = (yin0 && xin1) ? im[(ym << 8) + px] : 0.0f;
    float v10 = (yin1 && xin0) ? im[(py << 8) + xm] : 0.0f;
    float v11 = (yin1 && xin1) ? im[(py << 8) + px] : 0.0f;
    __half2 r0 = __floats2half2_rn(v00, v01);
    __half2 r1 = __floats2half2_rn(v10, v11);
    uint2 q;
    q.x = *reinterpret_cast<unsigned*>(&r0);
    q.y = *reinterpret_cast<unsigned*>(&r1);
    dst[idx] = q;
}

// Block = 256 threads = 64 rays x 4 sample-chunks (chunk == wave id).
__global__ __launch_bounds__(256) void fanproj_kernel(const uint2* __restrict__ quad,
                                                      float* __restrict__ out) {
    int lane  = threadIdx.x & 63;
    int chunk = threadIdx.x >> 6;                      // 0..3
    int ray   = (blockIdx.x << 6) + lane;              // b*P*D + p*D + d
    int d     = ray % NDET;
    int pb    = ray / NDET;
    int p     = pb & (NPROJ - 1);
    int b     = pb >> 8;

    const float dt = 1.4142135623730951f;              // diag / NS = sqrt(2)
    const float t0 = 219.68777079743137f;              // SID - diag/2 + 0.5*dt

    float theta = (float)p * (6.283185307179586f / (float)NPROJ);
    float st, ct;
    sincosf(theta, &st, &ct);

    float srcx = -400.0f * ct;
    float srcy = -400.0f * st;
    float off  = ((float)d - 191.5f) * 1.2f;
    float rx   = fmaf(800.0f, ct, -off * st);
    float ry   = fmaf(800.0f, st,  off * ct);
    float n2   = rx * rx + ry * ry;
    float rn   = rsqrtf(n2);
    rn = rn * (1.5f - 0.5f * n2 * rn * rn);            // one Newton step
    rx *= rn;
    ry *= rn;

    float bx = fmaf(t0, rx, srcx) + 127.5f;            // +(VOL-1)/2 folded in
    float by = fmaf(t0, ry, srcy) + 127.5f;
    float sx = dt * rx;
    float sy = dt * ry;

    const uint2* qimg = quad + b * PIMG;
    float acc = 0.0f;
    float sf  = (float)(chunk * SCHUNK);
#pragma unroll 4
    for (int s = 0; s < SCHUNK; ++s) {
        float x = fmaf(sf, sx, bx);
        float y = fmaf(sf, sy, by);
        sf += 1.0f;
        float xf = floorf(x);
        float yf = floorf(y);
        float wx = x - xf;
        float wy = y - yf;
        int x0 = (int)xf;
        int y0 = (int)yf;
        unsigned ux = (unsigned)(x0 + 1);              // quad col
        unsigned uy = (unsigned)(y0 + 1);              // quad row
        // x0,y0 in [-1,255]: footprint has at least one in-volume tap;
        // anything else contributes exactly 0 in the reference.
        if (ux <= 256u && uy <= 256u) {
            uint2 q = qimg[uy * PST + ux];             // whole 2x2 footprint, 8B
            __half2 h0 = *reinterpret_cast<__half2*>(&q.x);
            __half2 h1 = *reinterpret_cast<__half2*>(&q.y);
            float2 r0 = __half22float2(h0);
            float2 r1 = __half22float2(h1);
            float top = fmaf(wx, r0.y - r0.x, r0.x);
            float bot = fmaf(wx, r1.y - r1.x, r1.x);
            acc = fmaf(wy, bot - top, top) + acc;
        }
    }

    // reduce the 4 chunk-partials (one per wave) through LDS
    __shared__ float part[NCHUNK - 1][64];
    if (chunk > 0) part[chunk - 1][lane] = acc;
    __syncthreads();
    if (chunk == 0) {
        acc += part[0][lane] + part[1][lane] + part[2][lane];
        out[ray] = acc * dt;
    }
}

extern "C" void kernel_launch(void* const* d_in, const int* in_sizes, int n_in,
                              void* d_out, int out_size, void* d_ws, size_t ws_size,
                              hipStream_t stream) {
    const float* x  = (const float*)d_in[0];
    float* out      = (float*)d_out;
    uint2* quad     = (uint2*)d_ws;                    // NBATCH*PIMG*8B = 2.13 MB

    int npad = NBATCH * PIMG;                          // 133128
    quad_build_kernel<<<(npad + 255) / 256, 256, 0, stream>>>(x, quad);

    int nrays = NBATCH * NPROJ * NDET;                 // 196608
    fanproj_kernel<<<nrays / 64, 256, 0, stream>>>(quad, out);  // 3072 blocks
}